// Round 21
// baseline (509.062 us; speedup 1.0000x reference)
//
#include <hip/hip_runtime.h>
#include <math.h>

// ---------------------------------------------------------------------------
// 2-layer GAT on MI355X.
// R20 -> R21: returning global atomics proved ADDITIVE (~40us tax wherever
// placed; R17-R20 evidence). Replaced the whole atomic CSR build with an
// owner-computes scheme: dst-space split into 625-node ranges (64 L0 + 32
// L1 blocks). PhaseA (fused with weight-cvt): each range-block scans dst[]
// and appends its (eid,dst) pairs to a private segment (LDS-counter append,
// coalesced). PhaseB (per layer, after gemm): LDS histogram of the segment
// -> local scan -> offs for the range; ranks via LDS atomics; csr written
// directly into the block's contiguous region (L2-local, no amplification).
// Deletes 960k global atomics, global scans, scatter passes, rank arrays.
// perdst reverted to the proven 2-dst/wave batch-8 form (R20's 4-dst hurt).
// ---------------------------------------------------------------------------

#define D 128
#define RANGE 625   // dst nodes per range-block (40000/64, 20000/32)
#define CAP 16384   // segment capacity (avg 10000, max ~10500)

typedef __bf16 bf16x8 __attribute__((ext_vector_type(8)));
typedef float f32x4 __attribute__((ext_vector_type(4)));

static __device__ __forceinline__ float lrelu(float x) {
  return x >= 0.f ? x : 0.01f * x;
}
static __device__ __forceinline__ unsigned short f2bf(float v) {
  unsigned int u = __float_as_uint(v);
  u += 0x7fffu + ((u >> 16) & 1u);  // RNE
  return (unsigned short)(u >> 16);
}
static __device__ __forceinline__ float bf2f(unsigned short b) {
  return __uint_as_float((unsigned int)b << 16);
}

static __device__ __forceinline__ float4 loadV4(const float* p) {
  return *(const float4*)p;
}
static __device__ __forceinline__ float4 loadV4(const unsigned short* p) {
  ushort4 t = *(const ushort4*)p;
  return make_float4(bf2f(t.x), bf2f(t.y), bf2f(t.z), bf2f(t.w));
}
static __device__ __forceinline__ void storeV4(float* p, float4 v) {
  *(float4*)p = v;
}
static __device__ __forceinline__ void storeV4(unsigned short* p, float4 v) {
  ushort4 t;
  t.x = f2bf(v.x);
  t.y = f2bf(v.y);
  t.z = f2bf(v.z);
  t.w = f2bf(v.w);
  *(ushort4*)p = t;
}
static __device__ __forceinline__ void storeZi(float* p, float v) { *p = v; }
static __device__ __forceinline__ void storeZi(unsigned short* p, float v) {
  *p = f2bf(v);
}

// swizzled LDS byte offset for a [rows][128] bf16 tile (256B rows)
static __device__ __forceinline__ int swz(int row, int colb) {
  return row * 256 + (colb ^ ((row & 7) << 4));
}

// ---------------- front: weight cvt (blocks 0..255) + phaseA (256..351) ----
// phaseA block: owns dst range [lo, lo+RANGE) of its layer; scans the full
// dst array and appends (eid, dst) of in-range edges to its segment.
__global__ __launch_bounds__(256) void front_kernel(
    const float* __restrict__ s0, const float* __restrict__ s1,
    const float* __restrict__ s2, const float* __restrict__ s3,
    __bf16* __restrict__ wdst, const int* __restrict__ dst0,
    const int* __restrict__ dst1, int E0, int E1, int2* __restrict__ seg,
    int* __restrict__ total) {
  const int blk = blockIdx.x;
  const int t = threadIdx.x;
  if (blk < 256) {
    int idx = blk * 256 + t;  // 0..65535
    const float* s = (idx < 16384) ? s0
                     : (idx < 32768) ? s1
                     : (idx < 49152) ? s2 : s3;
    wdst[idx] = (__bf16)s[idx & 16383];
    return;
  }
  __shared__ int nseg;
  int g = blk - 256;  // 0..95
  const int* dst;
  int E, lo;
  if (g < 64) {
    dst = dst0; E = E0; lo = g * RANGE;
  } else {
    dst = dst1; E = E1; lo = (g - 64) * RANGE;
  }
  if (t == 0) nseg = 0;
  __syncthreads();
  int2* myseg = seg + (size_t)g * CAP;
  for (int i0 = t * 4; i0 < E; i0 += 1024) {
    int4 d4 = *(const int4*)(dst + i0);
    int dk[4] = {d4.x, d4.y, d4.z, d4.w};
#pragma unroll
    for (int k = 0; k < 4; ++k) {
      if (dk[k] >= lo && dk[k] < lo + RANGE) {
        int p = atomicAdd(&nseg, 1);
        if (p < CAP) myseg[p] = make_int2(i0 + k, dk[k]);
      }
    }
  }
  __syncthreads();
  if (t == 0) total[g] = (nseg < CAP) ? nseg : CAP;
}

// ---- A-tile staging into LDS (64 rows x 128 cols bf16, swizzled) ----------
static __device__ __forceinline__ void stageA(const float* A, int rblk,
                                              int rlim, int t,
                                              unsigned char* ldsA) {
  const char* base = (const char*)A + (size_t)rblk * 512;
#pragma unroll
  for (int g = 0; g < 8; ++g) {
    int sb = g * 4096 + t * 16;
    float4 v = make_float4(0.f, 0.f, 0.f, 0.f);
    if (rblk + (sb >> 9) < rlim) v = *(const float4*)(base + sb);
    int db = sb >> 1;
    int row = db >> 8, colb = db & 255;
    ushort4 o;
    o.x = f2bf(v.x);
    o.y = f2bf(v.y);
    o.z = f2bf(v.z);
    o.w = f2bf(v.w);
    *(ushort4*)(&ldsA[swz(row, colb)]) = o;
  }
}
static __device__ __forceinline__ void stageA(const unsigned short* A,
                                              int rblk, int rlim, int t,
                                              unsigned char* ldsA) {
  const char* base = (const char*)A + (size_t)rblk * 256;
#pragma unroll
  for (int g = 0; g < 4; ++g) {
    int bi = g * 4096 + t * 16;
    int row = bi >> 8, colb = bi & 255;
    ushort4 lo = {0, 0, 0, 0}, hi = {0, 0, 0, 0};
    if (rblk + row < rlim) {
      lo = *(const ushort4*)(base + bi);
      hi = *(const ushort4*)(base + bi + 8);
    }
    *(ushort4*)(&ldsA[swz(row, colb)]) = lo;
    *(ushort4*)(&ldsA[swz(row, colb) + 8]) = hi;
  }
}

// ---------------- LDS-staged MFMA GEMM over a flat block list (pure) -------
template <typename AT, typename ZiT>
__global__ __launch_bounds__(256, 3) void gemm_tiles(
    const AT* __restrict__ A, const __bf16* __restrict__ Wb,
    const __bf16* __restrict__ Ub, unsigned short* __restrict__ z,
    ZiT* __restrict__ zi, const float* __restrict__ a,
    float* __restrict__ zs, float* __restrict__ zd, int n_wb, int rows,
    int ndst) {
  __shared__ unsigned char lds[49152];  // B: [0,32768), A: [32768,49152)
  const int t = threadIdx.x;
  const int blk = blockIdx.x;
  const bool isU = (blk >= n_wb);
  const int rblk = (isU ? blk - n_wb : blk) * 64;
  const int rlim = isU ? ndst : rows;
  const __bf16* B = isU ? Ub : Wb;

#pragma unroll
  for (int g = 0; g < 8; ++g) {
    int bi = g * 4096 + t * 16;
    int row = bi >> 8, colb = bi & 255;
    bf16x8 v = *(const bf16x8*)((const char*)B + bi);
    *(bf16x8*)(&lds[swz(row, colb)]) = v;
  }
  stageA(A, rblk, rlim, t, lds + 32768);
  __syncthreads();

  const int wave = t >> 6;
  const int lane = t & 63;
  const int lm = lane & 15;
  const int lk = lane >> 4;
  const int r0 = rblk + wave * 16;
  if (r0 >= rlim) return;

  bf16x8 af[4];
#pragma unroll
  for (int kt = 0; kt < 4; ++kt) {
    int row = wave * 16 + lm;
    af[kt] = *(const bf16x8*)(&lds[32768 + swz(row, kt * 64 + lk * 16)]);
  }

  f32x4 acc[8];
#pragma unroll
  for (int tt = 0; tt < 8; ++tt) acc[tt] = (f32x4){0.f, 0.f, 0.f, 0.f};
#pragma unroll
  for (int kt = 0; kt < 4; ++kt) {
#pragma unroll
    for (int tt = 0; tt < 8; ++tt) {
      int row = tt * 16 + lm;
      bf16x8 bf = *(const bf16x8*)(&lds[swz(row, kt * 64 + lk * 16)]);
      acc[tt] =
          __builtin_amdgcn_mfma_f32_16x16x32_bf16(af[kt], bf, acc[tt], 0, 0, 0);
    }
  }

  if (!isU) {
#pragma unroll
    for (int tt = 0; tt < 8; ++tt)
#pragma unroll
      for (int rr = 0; rr < 4; ++rr)
        z[(size_t)(r0 + lk * 4 + rr) * D + tt * 16 + lm] = f2bf(acc[tt][rr]);

    float p1[4] = {0.f, 0.f, 0.f, 0.f};
    float p2[4] = {0.f, 0.f, 0.f, 0.f};
#pragma unroll
    for (int tt = 0; tt < 8; ++tt) {
      float a1 = a[tt * 16 + lm];
      float a2 = a[D + tt * 16 + lm];
#pragma unroll
      for (int rr = 0; rr < 4; ++rr) {
        p1[rr] += acc[tt][rr] * a1;
        p2[rr] += acc[tt][rr] * a2;
      }
    }
#pragma unroll
    for (int rr = 0; rr < 4; ++rr) {
#pragma unroll
      for (int o = 1; o < 16; o <<= 1) {
        p1[rr] += __shfl_xor(p1[rr], o);
        p2[rr] += __shfl_xor(p2[rr], o);
      }
      if (lm == 0) {
        zs[r0 + lk * 4 + rr] = p1[rr];
        zd[r0 + lk * 4 + rr] = p2[rr];
      }
    }
  } else {
#pragma unroll
    for (int tt = 0; tt < 8; ++tt)
#pragma unroll
      for (int rr = 0; rr < 4; ++rr)
        storeZi(&zi[(size_t)(r0 + lk * 4 + rr) * D + tt * 16 + lm],
                acc[tt][rr]);
  }
}

// ---------------- phaseB: per-range CSR build (no global atomics) ----------
// Block g owns dst range [g*RANGE, +RANGE). Histograms its segment in LDS,
// scans -> offs for the range (base = sum of earlier totals), then ranks
// via LDS atomics and writes csr entries into its contiguous region.
__global__ __launch_bounds__(256) void csr_phaseB(
    const int* __restrict__ src, const float* __restrict__ dE,
    const float* __restrict__ zs, const float* __restrict__ zd,
    const float* __restrict__ V, const float* __restrict__ a,
    const int2* __restrict__ seg, const int* __restrict__ total,
    int* __restrict__ offs, int2* __restrict__ csr, int gbase, int nblocks,
    int nd, int E) {
  __shared__ int hist[RANGE];
  __shared__ int loffs[RANGE];
  __shared__ int lrank[RANGE];
  __shared__ int swave[4];
  __shared__ int sbase;
  const int g = blockIdx.x;
  const int t = threadIdx.x;
  const int lo = g * RANGE;
  const int2* myseg = seg + (size_t)(gbase + g) * CAP;
  int nm = total[gbase + g];

  // pass 1: LDS histogram of the segment
  for (int j = t; j < RANGE; j += 256) {
    hist[j] = 0;
    lrank[j] = 0;
  }
  __syncthreads();
  for (int i = t; i < nm; i += 256) {
    int2 e = myseg[i];
    atomicAdd(&hist[e.y - lo], 1);
  }
  // base = sum of totals of earlier ranges (this layer)
  if (t < 64) {
    int v = (t < g && t < nblocks) ? total[gbase + t] : 0;
#pragma unroll
    for (int o = 32; o; o >>= 1) v += __shfl_xor(v, o);
    if (t == 0) sbase = v;
  }
  __syncthreads();

  // exclusive scan of hist -> loffs (3 contiguous elems per thread)
  int b3 = t * 3;
  int c0 = (b3 + 0 < RANGE) ? hist[b3 + 0] : 0;
  int c1 = (b3 + 1 < RANGE) ? hist[b3 + 1] : 0;
  int c2 = (b3 + 2 < RANGE) ? hist[b3 + 2] : 0;
  int ts = c0 + c1 + c2;
  int v = ts;
#pragma unroll
  for (int o = 1; o < 64; o <<= 1) {
    int u = __shfl_up(v, o);
    if ((t & 63) >= o) v += u;
  }
  if ((t & 63) == 63) swave[t >> 6] = v;
  __syncthreads();
  int w_ = t >> 6;
  int woff = 0;
  if (w_ > 0) woff += swave[0];
  if (w_ > 1) woff += swave[1];
  if (w_ > 2) woff += swave[2];
  int run = v - ts + woff;
  if (b3 + 0 < RANGE) { loffs[b3 + 0] = run; offs[lo + b3 + 0] = sbase + run; run += c0; }
  if (b3 + 1 < RANGE) { loffs[b3 + 1] = run; offs[lo + b3 + 1] = sbase + run; run += c1; }
  if (b3 + 2 < RANGE) { loffs[b3 + 2] = run; offs[lo + b3 + 2] = sbase + run; run += c2; }
  if (g == nblocks - 1 && t == 0) offs[nd] = E;
  __syncthreads();

  // pass 2: ranks + direct csr writes (contiguous region -> L2-local)
  float vc = V[0] * a[2 * D];
  int chunk = (nm + 255) >> 8;
  int bI = t * chunk;
  int eI = min(bI + chunk, nm);
  int i = bI;
  for (; i + 4 <= eI; i += 4) {
    int2 e[4];
#pragma unroll
    for (int k = 0; k < 4; ++k) e[k] = myseg[i + k];
    int ss[4];
    float de[4];
#pragma unroll
    for (int k = 0; k < 4; ++k) {
      ss[k] = src[e[k].x];
      de[k] = dE[e[k].x];
    }
    float zsv[4], zdv[4];
#pragma unroll
    for (int k = 0; k < 4; ++k) {
      zsv[k] = zs[ss[k]];
      zdv[k] = zd[e[k].y];
    }
#pragma unroll
    for (int k = 0; k < 4; ++k) {
      float w = __expf(lrelu(zsv[k] + zdv[k] + de[k] * vc));
      int dl = e[k].y - lo;
      int r = atomicAdd(&lrank[dl], 1);
      csr[sbase + loffs[dl] + r] = make_int2(ss[k], __float_as_int(w));
    }
  }
  for (; i < eI; ++i) {
    int2 e = myseg[i];
    int s = src[e.x];
    float w = __expf(lrelu(zs[s] + zd[e.y] + dE[e.x] * vc));
    int dl = e.y - lo;
    int r = atomicAdd(&lrank[dl], 1);
    csr[sbase + loffs[dl] + r] = make_int2(s, __float_as_int(w));
  }
}

// ---------------- per-dst: weighted accumulate (2 dst/wave, batch-8) -------
template <typename OT>
__global__ __launch_bounds__(256) void gat_perdst(
    const unsigned short* __restrict__ z, const int2* __restrict__ csr,
    const int* __restrict__ offs, const OT* __restrict__ ziin,
    OT* __restrict__ hout, int nd) {
  int n = blockIdx.x * 8 + (threadIdx.x >> 5);
  if (n >= nd) return;
  int lane = threadIdx.x & 31;
  int beg = offs[n], end = offs[n + 1];

  float s0 = 0.f, s1 = 0.f;
  float4 acc0 = make_float4(0.f, 0.f, 0.f, 0.f);
  float4 acc1 = make_float4(0.f, 0.f, 0.f, 0.f);
  const unsigned short* zp = z + lane * 4;
  int j = beg;
  for (; j + 8 <= end; j += 8) {
    int2 pr[8];
#pragma unroll
    for (int u = 0; u < 8; ++u) pr[u] = csr[j + u];
    float4 zv[8];
#pragma unroll
    for (int u = 0; u < 8; ++u) zv[u] = loadV4(zp + (size_t)pr[u].x * D);
#pragma unroll
    for (int u = 0; u < 8; u += 2) {
      float wa = __int_as_float(pr[u].y);
      float wb = __int_as_float(pr[u + 1].y);
      s0 += wa;
      acc0.x += wa * zv[u].x;
      acc0.y += wa * zv[u].y;
      acc0.z += wa * zv[u].z;
      acc0.w += wa * zv[u].w;
      s1 += wb;
      acc1.x += wb * zv[u + 1].x;
      acc1.y += wb * zv[u + 1].y;
      acc1.z += wb * zv[u + 1].z;
      acc1.w += wb * zv[u + 1].w;
    }
  }
  for (; j < end; ++j) {
    int2 pr = csr[j];
    float w = __int_as_float(pr.y);
    float4 zv = loadV4(zp + (size_t)pr.x * D);
    s0 += w;
    acc0.x += w * zv.x;
    acc0.y += w * zv.y;
    acc0.z += w * zv.z;
    acc0.w += w * zv.w;
  }
  float s = s0 + s1;
  float inv = (s > 0.f) ? 1.f / s : 0.f;
  float4 acc = make_float4(acc0.x + acc1.x, acc0.y + acc1.y, acc0.z + acc1.z,
                           acc0.w + acc1.w);
  float4 ziv = loadV4(ziin + (size_t)n * D + lane * 4);
  float4 o4;
  o4.x = fmaxf(ziv.x + acc.x * inv, 0.f);
  o4.y = fmaxf(ziv.y + acc.y * inv, 0.f);
  o4.z = fmaxf(ziv.z + acc.z * inv, 0.f);
  o4.w = fmaxf(ziv.w + acc.w * inv, 0.f);
  storeV4(hout + (size_t)n * D + lane * 4, o4);
}

// ---------------------------------------------------------------------------
extern "C" void kernel_launch(void* const* d_in, const int* in_sizes, int n_in,
                              void* d_out, int out_size, void* d_ws,
                              size_t ws_size, hipStream_t stream) {
  const float* attr = (const float*)d_in[0];
  const float* d0 = (const float*)d_in[1];
  const float* d1 = (const float*)d_in[2];
  const int* src0 = (const int*)d_in[3];
  const int* dst0 = (const int*)d_in[4];
  const int* src1 = (const int*)d_in[5];
  const int* dst1 = (const int*)d_in[6];
  const float* W0 = (const float*)d_in[9];
  const float* U0 = (const float*)d_in[10];
  const float* V0 = (const float*)d_in[11];
  const float* a0 = (const float*)d_in[12];
  const float* W1 = (const float*)d_in[13];
  const float* U1 = (const float*)d_in[14];
  const float* V1 = (const float*)d_in[15];
  const float* a1 = (const float*)d_in[16];

  const int N0 = in_sizes[0] / D;  // 100000
  const int E0 = in_sizes[1];      // 640000
  const int E1 = in_sizes[2];      // 320000
  const int ND0 = 40000;
  const int ND1 = 20000;

  char* p = (char*)d_ws;
  auto alloc = [&](size_t bytes) {
    char* q = p;
    p += (bytes + 255) & ~(size_t)255;
    return q;
  };
  unsigned short* z = (unsigned short*)alloc((size_t)N0 * D * 2);  // 25.6MB
  int2* csr = (int2*)alloc((size_t)E0 * 8);                        // 5.12MB
  unsigned short* h1b = (unsigned short*)alloc((size_t)ND0 * D * 2);  // 10.2MB
  int2* seg = (int2*)alloc((size_t)96 * CAP * 8);                     // 12.6MB
  int* total = (int*)alloc((size_t)96 * 4);
  float* zs = (float*)alloc((size_t)N0 * 4);
  float* zd = (float*)alloc((size_t)N0 * 4);
  int* offs0 = (int*)alloc((size_t)(ND0 + 1) * 4);
  int* offs1 = (int*)alloc((size_t)(ND1 + 1) * 4);
  __bf16* wb = (__bf16*)alloc((size_t)4 * D * D * 2);  // W0,U0,W1,U1 bf16
  (void)n_in;
  (void)out_size;
  (void)ws_size;

  float* out = (float*)d_out;

  // ---- front: weight cvt + phaseA (both layers) in one launch ----
  front_kernel<<<256 + 96, 256, 0, stream>>>(W0, U0, W1, U1, wb, dst0, dst1,
                                             E0, E1, seg, total);
  const __bf16* W0b = wb;
  const __bf16* U0b = wb + 16384;
  const __bf16* W1b = wb + 32768;
  const __bf16* U1b = wb + 49152;

  // ---- layer 0 GEMM (pure) ----
  {
    int n_wb = (N0 + 63) / 64, n_ub = (ND0 + 63) / 64;  // 1563 + 625
    gemm_tiles<float, unsigned short><<<n_wb + n_ub, 256, 0, stream>>>(
        attr, W0b, U0b, z, (unsigned short*)d_out, a0, zs, zd, n_wb, N0, ND0);
  }
  // ---- L0 CSR build (phaseB) ----
  csr_phaseB<<<64, 256, 0, stream>>>(src0, d0, zs, zd, V0, a0, seg, total,
                                     offs0, csr, 0, 64, ND0, E0);
  // ---- L0 aggregate ----
  gat_perdst<unsigned short><<<(ND0 + 7) / 8, 256, 0, stream>>>(
      z, csr, offs0, (const unsigned short*)d_out, h1b, ND0);

  // ---- layer 1 GEMM (pure) ----
  {
    int n_wb = (ND0 + 63) / 64, n_ub = (ND1 + 63) / 64;  // 625 + 313
    gemm_tiles<unsigned short, float><<<n_wb + n_ub, 256, 0, stream>>>(
        h1b, W1b, U1b, z, out, a1, zs, zd, n_wb, ND0, ND1);
  }
  // ---- L1 CSR build (phaseB) ----
  csr_phaseB<<<32, 256, 0, stream>>>(src1, d1, zs, zd, V1, a1, seg, total,
                                     offs1, csr, 64, 32, ND1, E1);
  // ---- L1 aggregate ----
  gat_perdst<float><<<(ND1 + 7) / 8, 256, 0, stream>>>(z, csr, offs1, out, out,
                                                       ND1);
}

// Round 22
// 152.459 us; speedup vs baseline: 3.3390x; 3.3390x over previous
//
#include <hip/hip_runtime.h>
#include <math.h>

// ---------------------------------------------------------------------------
// 2-layer GAT on MI355X.
// R21 -> R22: REVERT to the best-measured configuration (R19, 153.0us).
// R21's owner-computes CSR was serial-latency-bound (96 blocks x full-array
// scans, 375us). The returning-atomic path is a coherent-point throughput
// limit (~10 ops/cy chip-wide; padding/scope/planes/hiding all falsified);
// best schedule = all counts under gemm0, fused scans, pure scatter,
// 2-dst/wave batch-8 perdst.
// ---------------------------------------------------------------------------

#define D 128

typedef __bf16 bf16x8 __attribute__((ext_vector_type(8)));
typedef float f32x4 __attribute__((ext_vector_type(4)));

static __device__ __forceinline__ float lrelu(float x) {
  return x >= 0.f ? x : 0.01f * x;
}
static __device__ __forceinline__ unsigned short f2bf(float v) {
  unsigned int u = __float_as_uint(v);
  u += 0x7fffu + ((u >> 16) & 1u);  // RNE
  return (unsigned short)(u >> 16);
}
static __device__ __forceinline__ float bf2f(unsigned short b) {
  return __uint_as_float((unsigned int)b << 16);
}

static __device__ __forceinline__ float4 loadV4(const float* p) {
  return *(const float4*)p;
}
static __device__ __forceinline__ float4 loadV4(const unsigned short* p) {
  ushort4 t = *(const ushort4*)p;
  return make_float4(bf2f(t.x), bf2f(t.y), bf2f(t.z), bf2f(t.w));
}
static __device__ __forceinline__ void storeV4(float* p, float4 v) {
  *(float4*)p = v;
}
static __device__ __forceinline__ void storeV4(unsigned short* p, float4 v) {
  ushort4 t;
  t.x = f2bf(v.x);
  t.y = f2bf(v.y);
  t.z = f2bf(v.z);
  t.w = f2bf(v.w);
  *(ushort4*)p = t;
}
static __device__ __forceinline__ void storeZi(float* p, float v) { *p = v; }
static __device__ __forceinline__ void storeZi(unsigned short* p, float v) {
  *p = f2bf(v);
}

// swizzled LDS byte offset for a [rows][128] bf16 tile (256B rows)
static __device__ __forceinline__ int swz(int row, int colb) {
  return row * 256 + (colb ^ ((row & 7) << 4));
}

// ---- fused front matter: weight f32->bf16 + cnt zeroing -------------------
__global__ __launch_bounds__(256) void cvt4_zero_kernel(
    const float* __restrict__ s0, const float* __restrict__ s1,
    const float* __restrict__ s2, const float* __restrict__ s3,
    __bf16* __restrict__ dst, int* __restrict__ cnt, int nz) {
  int idx = blockIdx.x * 256 + threadIdx.x;
  if (idx < 65536) {
    const float* s = (idx < 16384) ? s0
                     : (idx < 32768) ? s1
                     : (idx < 49152) ? s2 : s3;
    dst[idx] = (__bf16)s[idx & 16383];
  } else if (idx - 65536 < nz) {
    cnt[idx - 65536] = 0;
  }
}

// ---- A-tile staging into LDS (64 rows x 128 cols bf16, swizzled) ----------
static __device__ __forceinline__ void stageA(const float* A, int rblk,
                                              int rlim, int t,
                                              unsigned char* ldsA) {
  const char* base = (const char*)A + (size_t)rblk * 512;
#pragma unroll
  for (int g = 0; g < 8; ++g) {
    int sb = g * 4096 + t * 16;  // src byte in 32KB f32 tile
    float4 v = make_float4(0.f, 0.f, 0.f, 0.f);
    if (rblk + (sb >> 9) < rlim) v = *(const float4*)(base + sb);
    int db = sb >> 1;  // dst byte in 16KB bf16 tile
    int row = db >> 8, colb = db & 255;
    ushort4 o;
    o.x = f2bf(v.x);
    o.y = f2bf(v.y);
    o.z = f2bf(v.z);
    o.w = f2bf(v.w);
    *(ushort4*)(&ldsA[swz(row, colb)]) = o;
  }
}
static __device__ __forceinline__ void stageA(const unsigned short* A,
                                              int rblk, int rlim, int t,
                                              unsigned char* ldsA) {
  const char* base = (const char*)A + (size_t)rblk * 256;
#pragma unroll
  for (int g = 0; g < 4; ++g) {
    int bi = g * 4096 + t * 16;  // byte in 16KB bf16 tile
    int row = bi >> 8, colb = bi & 255;
    ushort4 lo = {0, 0, 0, 0}, hi = {0, 0, 0, 0};
    if (rblk + row < rlim) {
      lo = *(const ushort4*)(base + bi);
      hi = *(const ushort4*)(base + bi + 8);
    }
    *(ushort4*)(&ldsA[swz(row, colb)]) = lo;
    *(ushort4*)(&ldsA[swz(row, colb) + 8]) = hi;
  }
}

// ---------------- fused: LDS-staged MFMA GEMM + count (both layers) --------
// blk % IL == 0 && blk/IL < nC -> count block: gid < q0 -> L0 edges,
// else L1 edges. Other blocks -> gemm block gb (W: z+zs+zd / U: zi).
// L1 launch reuses with nC=0, IL=1 (pure gemm).
template <typename AT, typename ZiT>
__global__ __launch_bounds__(256, 3) void gemm_count(
    const AT* __restrict__ A, const __bf16* __restrict__ Wb,
    const __bf16* __restrict__ Ub, unsigned short* __restrict__ z,
    ZiT* __restrict__ zi, const float* __restrict__ a,
    float* __restrict__ zs, float* __restrict__ zd, int n_wb, int rows,
    int ndst, const int* __restrict__ dst0, const int* __restrict__ dst1,
    int* __restrict__ cnt0, int* __restrict__ cnt1, int* __restrict__ rank0,
    int* __restrict__ rank1, int q0, int q1, int IL, int nC) {
  __shared__ unsigned char lds[49152];  // B: [0,32768), A: [32768,49152)
  const int blk = blockIdx.x;
  const int t = threadIdx.x;

  if ((blk % IL) == 0 && (blk / IL) < nC) {
    int gid = (blk / IL) * 256 + t;
    const int* dst;
    int* cnt;
    int* rank;
    int i0;
    if (gid < q0) {
      dst = dst0; cnt = cnt0; rank = rank0; i0 = gid * 4;
    } else if (gid < q0 + q1) {
      dst = dst1; cnt = cnt1; rank = rank1; i0 = (gid - q0) * 4;
    } else {
      return;
    }
    int4 d4 = *(const int4*)(dst + i0);
    int4 r4;
    r4.x = atomicAdd(&cnt[d4.x], 1);
    r4.y = atomicAdd(&cnt[d4.y], 1);
    r4.z = atomicAdd(&cnt[d4.z], 1);
    r4.w = atomicAdd(&cnt[d4.w], 1);
    *(int4*)(rank + i0) = r4;
    return;
  }
  const int cb = min(nC, (blk + IL - 1) / IL);  // count blocks before blk
  const int gb = blk - cb;

  const bool isU = (gb >= n_wb);
  const int rblk = (isU ? gb - n_wb : gb) * 64;
  const int rlim = isU ? ndst : rows;
  const __bf16* B = isU ? Ub : Wb;

#pragma unroll
  for (int g = 0; g < 8; ++g) {
    int bi = g * 4096 + t * 16;
    int row = bi >> 8, colb = bi & 255;
    bf16x8 v = *(const bf16x8*)((const char*)B + bi);
    *(bf16x8*)(&lds[swz(row, colb)]) = v;
  }
  stageA(A, rblk, rlim, t, lds + 32768);
  __syncthreads();

  const int wave = t >> 6;
  const int lane = t & 63;
  const int lm = lane & 15;
  const int lk = lane >> 4;
  const int r0 = rblk + wave * 16;
  if (r0 >= rlim) return;

  bf16x8 af[4];
#pragma unroll
  for (int kt = 0; kt < 4; ++kt) {
    int row = wave * 16 + lm;
    af[kt] = *(const bf16x8*)(&lds[32768 + swz(row, kt * 64 + lk * 16)]);
  }

  f32x4 acc[8];
#pragma unroll
  for (int tt = 0; tt < 8; ++tt) acc[tt] = (f32x4){0.f, 0.f, 0.f, 0.f};
#pragma unroll
  for (int kt = 0; kt < 4; ++kt) {
#pragma unroll
    for (int tt = 0; tt < 8; ++tt) {
      int row = tt * 16 + lm;
      bf16x8 bf = *(const bf16x8*)(&lds[swz(row, kt * 64 + lk * 16)]);
      acc[tt] =
          __builtin_amdgcn_mfma_f32_16x16x32_bf16(af[kt], bf, acc[tt], 0, 0, 0);
    }
  }

  if (!isU) {
#pragma unroll
    for (int tt = 0; tt < 8; ++tt)
#pragma unroll
      for (int rr = 0; rr < 4; ++rr)
        z[(size_t)(r0 + lk * 4 + rr) * D + tt * 16 + lm] = f2bf(acc[tt][rr]);

    float p1[4] = {0.f, 0.f, 0.f, 0.f};
    float p2[4] = {0.f, 0.f, 0.f, 0.f};
#pragma unroll
    for (int tt = 0; tt < 8; ++tt) {
      float a1 = a[tt * 16 + lm];
      float a2 = a[D + tt * 16 + lm];
#pragma unroll
      for (int rr = 0; rr < 4; ++rr) {
        p1[rr] += acc[tt][rr] * a1;
        p2[rr] += acc[tt][rr] * a2;
      }
    }
#pragma unroll
    for (int rr = 0; rr < 4; ++rr) {
#pragma unroll
      for (int o = 1; o < 16; o <<= 1) {
        p1[rr] += __shfl_xor(p1[rr], o);
        p2[rr] += __shfl_xor(p2[rr], o);
      }
      if (lm == 0) {
        zs[r0 + lk * 4 + rr] = p1[rr];
        zd[r0 + lk * 4 + rr] = p2[rr];
      }
    }
  } else {
#pragma unroll
    for (int tt = 0; tt < 8; ++tt)
#pragma unroll
      for (int rr = 0; rr < 4; ++rr)
        storeZi(&zi[(size_t)(r0 + lk * 4 + rr) * D + tt * 16 + lm],
                acc[tt][rr]);
  }
}

// ---------------- scans (both layers in one launch) ------------------------
__global__ __launch_bounds__(256) void scan_partial2(
    const int* __restrict__ cnt0, const int* __restrict__ cnt1,
    int* __restrict__ part, int nb0, int n0, int n1) {
  __shared__ int sm[4];
  int blk = blockIdx.x;
  const int* cnt;
  int* pt;
  int n, lb;
  if (blk < nb0) {
    cnt = cnt0; pt = part; n = n0; lb = blk;
  } else {
    cnt = cnt1; pt = part + 64; n = n1; lb = blk - nb0;
  }
  int base = lb * 1024;
  int t = threadIdx.x;
  int s = 0;
#pragma unroll
  for (int i = 0; i < 4; ++i) {
    int idx = base + t + i * 256;
    s += (idx < n) ? cnt[idx] : 0;
  }
  for (int o = 32; o; o >>= 1) s += __shfl_xor(s, o);
  if ((t & 63) == 0) sm[t >> 6] = s;
  __syncthreads();
  if (t == 0) pt[lb] = sm[0] + sm[1] + sm[2] + sm[3];
}

__global__ __launch_bounds__(256) void scan_final2(
    const int* __restrict__ cnt0, const int* __restrict__ cnt1,
    const int* __restrict__ part, int* __restrict__ offs0,
    int* __restrict__ offs1, int nb0, int n0, int n1, int tot0, int tot1) {
  __shared__ int sm[4];
  __shared__ int sbase;
  int blk = blockIdx.x;
  const int* cnt;
  const int* pt;
  int* offs;
  int n, lb, total;
  if (blk < nb0) {
    cnt = cnt0; pt = part; offs = offs0; n = n0; lb = blk; total = tot0;
  } else {
    cnt = cnt1; pt = part + 64; offs = offs1; n = n1; lb = blk - nb0;
    total = tot1;
  }
  int base = lb * 1024;
  int t = threadIdx.x;
  if (t < 64) {
    int v = (t < lb) ? pt[t] : 0;
#pragma unroll
    for (int o = 32; o; o >>= 1) v += __shfl_xor(v, o);
    if (t == 0) sbase = v;
  }
  int idx = base + t * 4;
  int c0 = (idx + 0 < n) ? cnt[idx + 0] : 0;
  int c1 = (idx + 1 < n) ? cnt[idx + 1] : 0;
  int c2 = (idx + 2 < n) ? cnt[idx + 2] : 0;
  int c3 = (idx + 3 < n) ? cnt[idx + 3] : 0;
  int ts = c0 + c1 + c2 + c3;
  int v = ts;
#pragma unroll
  for (int o = 1; o < 64; o <<= 1) {
    int u = __shfl_up(v, o);
    if ((t & 63) >= o) v += u;
  }
  if ((t & 63) == 63) sm[t >> 6] = v;
  __syncthreads();
  int w = t >> 6;
  int waveoff = 0;
  if (w > 0) waveoff += sm[0];
  if (w > 1) waveoff += sm[1];
  if (w > 2) waveoff += sm[2];
  int run = v - ts + waveoff + sbase;
  if (idx + 0 < n) { offs[idx + 0] = run; run += c0; }
  if (idx + 1 < n) { offs[idx + 1] = run; run += c1; }
  if (idx + 2 < n) { offs[idx + 2] = run; run += c2; }
  if (idx + 3 < n) { offs[idx + 3] = run; run += c3; }
  if (lb == 0 && t == 0) offs[n] = total;
}

// scatter + w-compute: p = offs[dst] + rank; csr[p] = (src, exp(lrelu(e)))
__global__ void scatter_w_kernel(const int* __restrict__ src,
                                 const int* __restrict__ dst,
                                 const float* __restrict__ dE,
                                 const float* __restrict__ zs,
                                 const float* __restrict__ zd,
                                 const float* __restrict__ V,
                                 const float* __restrict__ a,
                                 const int* __restrict__ rank,
                                 const int* __restrict__ offs,
                                 int2* __restrict__ csr, int E) {
  int i0 = (blockIdx.x * 256 + threadIdx.x) * 4;
  float vc = V[0] * a[2 * D];
  if (i0 + 4 <= E) {
    int4 s4 = *(const int4*)(src + i0);
    int4 d4 = *(const int4*)(dst + i0);
    float4 de = *(const float4*)(dE + i0);
    int4 r4 = *(const int4*)(rank + i0);
    float zs0 = zs[s4.x], zs1 = zs[s4.y], zs2 = zs[s4.z], zs3 = zs[s4.w];
    float zd0 = zd[d4.x], zd1 = zd[d4.y], zd2 = zd[d4.z], zd3 = zd[d4.w];
    int p0 = offs[d4.x] + r4.x;
    int p1 = offs[d4.y] + r4.y;
    int p2 = offs[d4.z] + r4.z;
    int p3 = offs[d4.w] + r4.w;
    float w0 = __expf(lrelu(zs0 + zd0 + de.x * vc));
    float w1 = __expf(lrelu(zs1 + zd1 + de.y * vc));
    float w2 = __expf(lrelu(zs2 + zd2 + de.z * vc));
    float w3 = __expf(lrelu(zs3 + zd3 + de.w * vc));
    csr[p0] = make_int2(s4.x, __float_as_int(w0));
    csr[p1] = make_int2(s4.y, __float_as_int(w1));
    csr[p2] = make_int2(s4.z, __float_as_int(w2));
    csr[p3] = make_int2(s4.w, __float_as_int(w3));
  } else {
    for (int i = i0; i < E; ++i) {
      int di = dst[i];
      int pp = offs[di] + rank[i];
      float w = __expf(lrelu(zs[src[i]] + zd[di] + dE[i] * vc));
      csr[pp] = make_int2(src[i], __float_as_int(w));
    }
  }
}

// ---------------- per-dst: weighted accumulate (w precomputed) -------------
template <typename OT>
__global__ __launch_bounds__(256) void gat_perdst(
    const unsigned short* __restrict__ z, const int2* __restrict__ csr,
    const int* __restrict__ offs, const OT* __restrict__ ziin,
    OT* __restrict__ hout, int nd) {
  int n = blockIdx.x * 8 + (threadIdx.x >> 5);
  if (n >= nd) return;
  int lane = threadIdx.x & 31;
  int beg = offs[n], end = offs[n + 1];

  float s0 = 0.f, s1 = 0.f;
  float4 acc0 = make_float4(0.f, 0.f, 0.f, 0.f);
  float4 acc1 = make_float4(0.f, 0.f, 0.f, 0.f);
  const unsigned short* zp = z + lane * 4;
  int j = beg;
  for (; j + 8 <= end; j += 8) {
    int2 pr[8];
#pragma unroll
    for (int u = 0; u < 8; ++u) pr[u] = csr[j + u];
    float4 zv[8];
#pragma unroll
    for (int u = 0; u < 8; ++u) zv[u] = loadV4(zp + (size_t)pr[u].x * D);
#pragma unroll
    for (int u = 0; u < 8; u += 2) {
      float wa = __int_as_float(pr[u].y);
      float wb = __int_as_float(pr[u + 1].y);
      s0 += wa;
      acc0.x += wa * zv[u].x;
      acc0.y += wa * zv[u].y;
      acc0.z += wa * zv[u].z;
      acc0.w += wa * zv[u].w;
      s1 += wb;
      acc1.x += wb * zv[u + 1].x;
      acc1.y += wb * zv[u + 1].y;
      acc1.z += wb * zv[u + 1].z;
      acc1.w += wb * zv[u + 1].w;
    }
  }
  for (; j < end; ++j) {
    int2 pr = csr[j];
    float w = __int_as_float(pr.y);
    float4 zv = loadV4(zp + (size_t)pr.x * D);
    s0 += w;
    acc0.x += w * zv.x;
    acc0.y += w * zv.y;
    acc0.z += w * zv.z;
    acc0.w += w * zv.w;
  }
  float s = s0 + s1;
  float inv = (s > 0.f) ? 1.f / s : 0.f;
  float4 acc = make_float4(acc0.x + acc1.x, acc0.y + acc1.y, acc0.z + acc1.z,
                           acc0.w + acc1.w);
  float4 ziv = loadV4(ziin + (size_t)n * D + lane * 4);
  float4 o4;
  o4.x = fmaxf(ziv.x + acc.x * inv, 0.f);
  o4.y = fmaxf(ziv.y + acc.y * inv, 0.f);
  o4.z = fmaxf(ziv.z + acc.z * inv, 0.f);
  o4.w = fmaxf(ziv.w + acc.w * inv, 0.f);
  storeV4(hout + (size_t)n * D + lane * 4, o4);
}

// ---------------------------------------------------------------------------
extern "C" void kernel_launch(void* const* d_in, const int* in_sizes, int n_in,
                              void* d_out, int out_size, void* d_ws,
                              size_t ws_size, hipStream_t stream) {
  const float* attr = (const float*)d_in[0];
  const float* d0 = (const float*)d_in[1];
  const float* d1 = (const float*)d_in[2];
  const int* src0 = (const int*)d_in[3];
  const int* dst0 = (const int*)d_in[4];
  const int* src1 = (const int*)d_in[5];
  const int* dst1 = (const int*)d_in[6];
  const float* W0 = (const float*)d_in[9];
  const float* U0 = (const float*)d_in[10];
  const float* V0 = (const float*)d_in[11];
  const float* a0 = (const float*)d_in[12];
  const float* W1 = (const float*)d_in[13];
  const float* U1 = (const float*)d_in[14];
  const float* V1 = (const float*)d_in[15];
  const float* a1 = (const float*)d_in[16];

  const int N0 = in_sizes[0] / D;  // 100000
  const int E0 = in_sizes[1];      // 640000
  const int E1 = in_sizes[2];      // 320000
  const int ND0 = 40000;
  const int ND1 = 20000;

  char* p = (char*)d_ws;
  auto alloc = [&](size_t bytes) {
    char* q = p;
    p += (bytes + 255) & ~(size_t)255;
    return q;
  };
  unsigned short* z = (unsigned short*)alloc((size_t)N0 * D * 2);  // 25.6MB
  int2* csr = (int2*)alloc((size_t)E0 * 8);                        // 5.12MB
  unsigned short* h1b = (unsigned short*)alloc((size_t)ND0 * D * 2);  // 10.2MB
  int* rank0 = (int*)alloc((size_t)E0 * 4);                           // 2.56MB
  int* rank1 = (int*)alloc((size_t)E1 * 4);                           // 1.28MB
  float* zs = (float*)alloc((size_t)N0 * 4);
  float* zd = (float*)alloc((size_t)N0 * 4);
  int* offs0 = (int*)alloc((size_t)(ND0 + 1) * 4);
  int* offs1 = (int*)alloc((size_t)(ND1 + 1) * 4);
  int* cnt01 = (int*)alloc((size_t)(ND0 + ND1) * 4);  // 240KB
  int* part = (int*)alloc((size_t)128 * 4);           // 64 per layer
  __bf16* wb = (__bf16*)alloc((size_t)4 * D * D * 2);  // W0,U0,W1,U1 bf16
  int* cnt0 = cnt01;
  int* cnt1 = cnt01 + ND0;
  (void)n_in;
  (void)out_size;
  (void)ws_size;

  float* out = (float*)d_out;

  // ---- front matter: weights cvt + cnt zero in ONE launch ----
  {
    int tot = 65536 + ND0 + ND1;
    cvt4_zero_kernel<<<(tot + 255) / 256, 256, 0, stream>>>(
        W0, U0, W1, U1, wb, cnt01, ND0 + ND1);
  }
  const __bf16* W0b = wb;
  const __bf16* U0b = wb + 16384;
  const __bf16* W1b = wb + 32768;
  const __bf16* U1b = wb + 49152;

  // ---- layer 0 GEMM fused with ALL counts (L0 + L1) ----
  {
    int q0 = E0 / 4, q1 = E1 / 4;     // 160000, 80000 (exact)
    int nC = (q0 + q1 + 255) / 256;   // 938
    int n_wb = (N0 + 63) / 64;        // 1563
    int n_ub = (ND0 + 63) / 64;       // 625
    int total = n_wb + n_ub + nC;     // 3126
    int IL = total / nC;              // 3
    gemm_count<float, unsigned short><<<total, 256, 0, stream>>>(
        attr, W0b, U0b, z, (unsigned short*)d_out, a0, zs, zd, n_wb, N0, ND0,
        dst0, dst1, cnt0, cnt1, rank0, rank1, q0, q1, IL, nC);
  }
  // ---- both layers' scans ----
  {
    int nb0 = (ND0 + 1023) / 1024;  // 40
    int nb1 = (ND1 + 1023) / 1024;  // 20
    scan_partial2<<<nb0 + nb1, 256, 0, stream>>>(cnt0, cnt1, part, nb0, ND0,
                                                 ND1);
    scan_final2<<<nb0 + nb1, 256, 0, stream>>>(cnt0, cnt1, part, offs0, offs1,
                                               nb0, ND0, ND1, E0, E1);
  }
  // ---- layer 0: scatter + aggregate ----
  scatter_w_kernel<<<(E0 / 4 + 255) / 256, 256, 0, stream>>>(
      src0, dst0, d0, zs, zd, V0, a0, rank0, offs0, csr, E0);
  gat_perdst<unsigned short><<<(ND0 + 7) / 8, 256, 0, stream>>>(
      z, csr, offs0, (const unsigned short*)d_out, h1b, ND0);

  // ---- layer 1 (pure gemm via nC=0) ----
  {
    int n_wb = (ND0 + 63) / 64, n_ub = (ND1 + 63) / 64;  // 625 + 313
    gemm_count<unsigned short, float><<<n_wb + n_ub, 256, 0, stream>>>(
        h1b, W1b, U1b, z, out, a1, zs, zd, n_wb, ND0, ND1, nullptr, nullptr,
        nullptr, nullptr, nullptr, nullptr, 0, 0, 1, 0);
  }
  scatter_w_kernel<<<(E1 / 4 + 255) / 256, 256, 0, stream>>>(
      src1, dst1, d1, zs, zd, V1, a1, rank1, offs1, csr, E1);
  gat_perdst<float><<<(ND1 + 7) / 8, 256, 0, stream>>>(z, csr, offs1, out, out,
                                                       ND1);
}

// Round 23
// 150.424 us; speedup vs baseline: 3.3842x; 1.0135x over previous
//
#include <hip/hip_runtime.h>
#include <math.h>

// ---------------------------------------------------------------------------
// 2-layer GAT on MI355X.
// R22 -> R23: single change -- perdst's scalar tail (deg mod 8, ~22% of
// edges, each paying the full ~600cy gather chain serially) replaced by a
// predicated full-width batch: indices clamped to end-1, weights zeroed for
// out-of-range slots. Every edge now gets 8-deep MLP; clamped duplicate
// loads are same-address (cheap). Numerically exact (adds zeros).
// Everything else identical to R22 (the measured 152.5us optimum).
// ---------------------------------------------------------------------------

#define D 128

typedef __bf16 bf16x8 __attribute__((ext_vector_type(8)));
typedef float f32x4 __attribute__((ext_vector_type(4)));

static __device__ __forceinline__ float lrelu(float x) {
  return x >= 0.f ? x : 0.01f * x;
}
static __device__ __forceinline__ unsigned short f2bf(float v) {
  unsigned int u = __float_as_uint(v);
  u += 0x7fffu + ((u >> 16) & 1u);  // RNE
  return (unsigned short)(u >> 16);
}
static __device__ __forceinline__ float bf2f(unsigned short b) {
  return __uint_as_float((unsigned int)b << 16);
}

static __device__ __forceinline__ float4 loadV4(const float* p) {
  return *(const float4*)p;
}
static __device__ __forceinline__ float4 loadV4(const unsigned short* p) {
  ushort4 t = *(const ushort4*)p;
  return make_float4(bf2f(t.x), bf2f(t.y), bf2f(t.z), bf2f(t.w));
}
static __device__ __forceinline__ void storeV4(float* p, float4 v) {
  *(float4*)p = v;
}
static __device__ __forceinline__ void storeV4(unsigned short* p, float4 v) {
  ushort4 t;
  t.x = f2bf(v.x);
  t.y = f2bf(v.y);
  t.z = f2bf(v.z);
  t.w = f2bf(v.w);
  *(ushort4*)p = t;
}
static __device__ __forceinline__ void storeZi(float* p, float v) { *p = v; }
static __device__ __forceinline__ void storeZi(unsigned short* p, float v) {
  *p = f2bf(v);
}

// swizzled LDS byte offset for a [rows][128] bf16 tile (256B rows)
static __device__ __forceinline__ int swz(int row, int colb) {
  return row * 256 + (colb ^ ((row & 7) << 4));
}

// ---- fused front matter: weight f32->bf16 + cnt zeroing -------------------
__global__ __launch_bounds__(256) void cvt4_zero_kernel(
    const float* __restrict__ s0, const float* __restrict__ s1,
    const float* __restrict__ s2, const float* __restrict__ s3,
    __bf16* __restrict__ dst, int* __restrict__ cnt, int nz) {
  int idx = blockIdx.x * 256 + threadIdx.x;
  if (idx < 65536) {
    const float* s = (idx < 16384) ? s0
                     : (idx < 32768) ? s1
                     : (idx < 49152) ? s2 : s3;
    dst[idx] = (__bf16)s[idx & 16383];
  } else if (idx - 65536 < nz) {
    cnt[idx - 65536] = 0;
  }
}

// ---- A-tile staging into LDS (64 rows x 128 cols bf16, swizzled) ----------
static __device__ __forceinline__ void stageA(const float* A, int rblk,
                                              int rlim, int t,
                                              unsigned char* ldsA) {
  const char* base = (const char*)A + (size_t)rblk * 512;
#pragma unroll
  for (int g = 0; g < 8; ++g) {
    int sb = g * 4096 + t * 16;  // src byte in 32KB f32 tile
    float4 v = make_float4(0.f, 0.f, 0.f, 0.f);
    if (rblk + (sb >> 9) < rlim) v = *(const float4*)(base + sb);
    int db = sb >> 1;  // dst byte in 16KB bf16 tile
    int row = db >> 8, colb = db & 255;
    ushort4 o;
    o.x = f2bf(v.x);
    o.y = f2bf(v.y);
    o.z = f2bf(v.z);
    o.w = f2bf(v.w);
    *(ushort4*)(&ldsA[swz(row, colb)]) = o;
  }
}
static __device__ __forceinline__ void stageA(const unsigned short* A,
                                              int rblk, int rlim, int t,
                                              unsigned char* ldsA) {
  const char* base = (const char*)A + (size_t)rblk * 256;
#pragma unroll
  for (int g = 0; g < 4; ++g) {
    int bi = g * 4096 + t * 16;  // byte in 16KB bf16 tile
    int row = bi >> 8, colb = bi & 255;
    ushort4 lo = {0, 0, 0, 0}, hi = {0, 0, 0, 0};
    if (rblk + row < rlim) {
      lo = *(const ushort4*)(base + bi);
      hi = *(const ushort4*)(base + bi + 8);
    }
    *(ushort4*)(&ldsA[swz(row, colb)]) = lo;
    *(ushort4*)(&ldsA[swz(row, colb) + 8]) = hi;
  }
}

// ---------------- fused: LDS-staged MFMA GEMM + count (both layers) --------
template <typename AT, typename ZiT>
__global__ __launch_bounds__(256, 3) void gemm_count(
    const AT* __restrict__ A, const __bf16* __restrict__ Wb,
    const __bf16* __restrict__ Ub, unsigned short* __restrict__ z,
    ZiT* __restrict__ zi, const float* __restrict__ a,
    float* __restrict__ zs, float* __restrict__ zd, int n_wb, int rows,
    int ndst, const int* __restrict__ dst0, const int* __restrict__ dst1,
    int* __restrict__ cnt0, int* __restrict__ cnt1, int* __restrict__ rank0,
    int* __restrict__ rank1, int q0, int q1, int IL, int nC) {
  __shared__ unsigned char lds[49152];  // B: [0,32768), A: [32768,49152)
  const int blk = blockIdx.x;
  const int t = threadIdx.x;

  if ((blk % IL) == 0 && (blk / IL) < nC) {
    int gid = (blk / IL) * 256 + t;
    const int* dst;
    int* cnt;
    int* rank;
    int i0;
    if (gid < q0) {
      dst = dst0; cnt = cnt0; rank = rank0; i0 = gid * 4;
    } else if (gid < q0 + q1) {
      dst = dst1; cnt = cnt1; rank = rank1; i0 = (gid - q0) * 4;
    } else {
      return;
    }
    int4 d4 = *(const int4*)(dst + i0);
    int4 r4;
    r4.x = atomicAdd(&cnt[d4.x], 1);
    r4.y = atomicAdd(&cnt[d4.y], 1);
    r4.z = atomicAdd(&cnt[d4.z], 1);
    r4.w = atomicAdd(&cnt[d4.w], 1);
    *(int4*)(rank + i0) = r4;
    return;
  }
  const int cb = min(nC, (blk + IL - 1) / IL);  // count blocks before blk
  const int gb = blk - cb;

  const bool isU = (gb >= n_wb);
  const int rblk = (isU ? gb - n_wb : gb) * 64;
  const int rlim = isU ? ndst : rows;
  const __bf16* B = isU ? Ub : Wb;

#pragma unroll
  for (int g = 0; g < 8; ++g) {
    int bi = g * 4096 + t * 16;
    int row = bi >> 8, colb = bi & 255;
    bf16x8 v = *(const bf16x8*)((const char*)B + bi);
    *(bf16x8*)(&lds[swz(row, colb)]) = v;
  }
  stageA(A, rblk, rlim, t, lds + 32768);
  __syncthreads();

  const int wave = t >> 6;
  const int lane = t & 63;
  const int lm = lane & 15;
  const int lk = lane >> 4;
  const int r0 = rblk + wave * 16;
  if (r0 >= rlim) return;

  bf16x8 af[4];
#pragma unroll
  for (int kt = 0; kt < 4; ++kt) {
    int row = wave * 16 + lm;
    af[kt] = *(const bf16x8*)(&lds[32768 + swz(row, kt * 64 + lk * 16)]);
  }

  f32x4 acc[8];
#pragma unroll
  for (int tt = 0; tt < 8; ++tt) acc[tt] = (f32x4){0.f, 0.f, 0.f, 0.f};
#pragma unroll
  for (int kt = 0; kt < 4; ++kt) {
#pragma unroll
    for (int tt = 0; tt < 8; ++tt) {
      int row = tt * 16 + lm;
      bf16x8 bf = *(const bf16x8*)(&lds[swz(row, kt * 64 + lk * 16)]);
      acc[tt] =
          __builtin_amdgcn_mfma_f32_16x16x32_bf16(af[kt], bf, acc[tt], 0, 0, 0);
    }
  }

  if (!isU) {
#pragma unroll
    for (int tt = 0; tt < 8; ++tt)
#pragma unroll
      for (int rr = 0; rr < 4; ++rr)
        z[(size_t)(r0 + lk * 4 + rr) * D + tt * 16 + lm] = f2bf(acc[tt][rr]);

    float p1[4] = {0.f, 0.f, 0.f, 0.f};
    float p2[4] = {0.f, 0.f, 0.f, 0.f};
#pragma unroll
    for (int tt = 0; tt < 8; ++tt) {
      float a1 = a[tt * 16 + lm];
      float a2 = a[D + tt * 16 + lm];
#pragma unroll
      for (int rr = 0; rr < 4; ++rr) {
        p1[rr] += acc[tt][rr] * a1;
        p2[rr] += acc[tt][rr] * a2;
      }
    }
#pragma unroll
    for (int rr = 0; rr < 4; ++rr) {
#pragma unroll
      for (int o = 1; o < 16; o <<= 1) {
        p1[rr] += __shfl_xor(p1[rr], o);
        p2[rr] += __shfl_xor(p2[rr], o);
      }
      if (lm == 0) {
        zs[r0 + lk * 4 + rr] = p1[rr];
        zd[r0 + lk * 4 + rr] = p2[rr];
      }
    }
  } else {
#pragma unroll
    for (int tt = 0; tt < 8; ++tt)
#pragma unroll
      for (int rr = 0; rr < 4; ++rr)
        storeZi(&zi[(size_t)(r0 + lk * 4 + rr) * D + tt * 16 + lm],
                acc[tt][rr]);
  }
}

// ---------------- scans (both layers in one launch) ------------------------
__global__ __launch_bounds__(256) void scan_partial2(
    const int* __restrict__ cnt0, const int* __restrict__ cnt1,
    int* __restrict__ part, int nb0, int n0, int n1) {
  __shared__ int sm[4];
  int blk = blockIdx.x;
  const int* cnt;
  int* pt;
  int n, lb;
  if (blk < nb0) {
    cnt = cnt0; pt = part; n = n0; lb = blk;
  } else {
    cnt = cnt1; pt = part + 64; n = n1; lb = blk - nb0;
  }
  int base = lb * 1024;
  int t = threadIdx.x;
  int s = 0;
#pragma unroll
  for (int i = 0; i < 4; ++i) {
    int idx = base + t + i * 256;
    s += (idx < n) ? cnt[idx] : 0;
  }
  for (int o = 32; o; o >>= 1) s += __shfl_xor(s, o);
  if ((t & 63) == 0) sm[t >> 6] = s;
  __syncthreads();
  if (t == 0) pt[lb] = sm[0] + sm[1] + sm[2] + sm[3];
}

__global__ __launch_bounds__(256) void scan_final2(
    const int* __restrict__ cnt0, const int* __restrict__ cnt1,
    const int* __restrict__ part, int* __restrict__ offs0,
    int* __restrict__ offs1, int nb0, int n0, int n1, int tot0, int tot1) {
  __shared__ int sm[4];
  __shared__ int sbase;
  int blk = blockIdx.x;
  const int* cnt;
  const int* pt;
  int* offs;
  int n, lb, total;
  if (blk < nb0) {
    cnt = cnt0; pt = part; offs = offs0; n = n0; lb = blk; total = tot0;
  } else {
    cnt = cnt1; pt = part + 64; offs = offs1; n = n1; lb = blk - nb0;
    total = tot1;
  }
  int base = lb * 1024;
  int t = threadIdx.x;
  if (t < 64) {
    int v = (t < lb) ? pt[t] : 0;
#pragma unroll
    for (int o = 32; o; o >>= 1) v += __shfl_xor(v, o);
    if (t == 0) sbase = v;
  }
  int idx = base + t * 4;
  int c0 = (idx + 0 < n) ? cnt[idx + 0] : 0;
  int c1 = (idx + 1 < n) ? cnt[idx + 1] : 0;
  int c2 = (idx + 2 < n) ? cnt[idx + 2] : 0;
  int c3 = (idx + 3 < n) ? cnt[idx + 3] : 0;
  int ts = c0 + c1 + c2 + c3;
  int v = ts;
#pragma unroll
  for (int o = 1; o < 64; o <<= 1) {
    int u = __shfl_up(v, o);
    if ((t & 63) >= o) v += u;
  }
  if ((t & 63) == 63) sm[t >> 6] = v;
  __syncthreads();
  int w = t >> 6;
  int waveoff = 0;
  if (w > 0) waveoff += sm[0];
  if (w > 1) waveoff += sm[1];
  if (w > 2) waveoff += sm[2];
  int run = v - ts + waveoff + sbase;
  if (idx + 0 < n) { offs[idx + 0] = run; run += c0; }
  if (idx + 1 < n) { offs[idx + 1] = run; run += c1; }
  if (idx + 2 < n) { offs[idx + 2] = run; run += c2; }
  if (idx + 3 < n) { offs[idx + 3] = run; run += c3; }
  if (lb == 0 && t == 0) offs[n] = total;
}

// scatter + w-compute: p = offs[dst] + rank; csr[p] = (src, exp(lrelu(e)))
__global__ void scatter_w_kernel(const int* __restrict__ src,
                                 const int* __restrict__ dst,
                                 const float* __restrict__ dE,
                                 const float* __restrict__ zs,
                                 const float* __restrict__ zd,
                                 const float* __restrict__ V,
                                 const float* __restrict__ a,
                                 const int* __restrict__ rank,
                                 const int* __restrict__ offs,
                                 int2* __restrict__ csr, int E) {
  int i0 = (blockIdx.x * 256 + threadIdx.x) * 4;
  float vc = V[0] * a[2 * D];
  if (i0 + 4 <= E) {
    int4 s4 = *(const int4*)(src + i0);
    int4 d4 = *(const int4*)(dst + i0);
    float4 de = *(const float4*)(dE + i0);
    int4 r4 = *(const int4*)(rank + i0);
    float zs0 = zs[s4.x], zs1 = zs[s4.y], zs2 = zs[s4.z], zs3 = zs[s4.w];
    float zd0 = zd[d4.x], zd1 = zd[d4.y], zd2 = zd[d4.z], zd3 = zd[d4.w];
    int p0 = offs[d4.x] + r4.x;
    int p1 = offs[d4.y] + r4.y;
    int p2 = offs[d4.z] + r4.z;
    int p3 = offs[d4.w] + r4.w;
    float w0 = __expf(lrelu(zs0 + zd0 + de.x * vc));
    float w1 = __expf(lrelu(zs1 + zd1 + de.y * vc));
    float w2 = __expf(lrelu(zs2 + zd2 + de.z * vc));
    float w3 = __expf(lrelu(zs3 + zd3 + de.w * vc));
    csr[p0] = make_int2(s4.x, __float_as_int(w0));
    csr[p1] = make_int2(s4.y, __float_as_int(w1));
    csr[p2] = make_int2(s4.z, __float_as_int(w2));
    csr[p3] = make_int2(s4.w, __float_as_int(w3));
  } else {
    for (int i = i0; i < E; ++i) {
      int di = dst[i];
      int pp = offs[di] + rank[i];
      float w = __expf(lrelu(zs[src[i]] + zd[di] + dE[i] * vc));
      csr[pp] = make_int2(src[i], __float_as_int(w));
    }
  }
}

// ---------------- per-dst: weighted accumulate (predicated 8-wide) ---------
template <typename OT>
__global__ __launch_bounds__(256) void gat_perdst(
    const unsigned short* __restrict__ z, const int2* __restrict__ csr,
    const int* __restrict__ offs, const OT* __restrict__ ziin,
    OT* __restrict__ hout, int nd) {
  int n = blockIdx.x * 8 + (threadIdx.x >> 5);
  if (n >= nd) return;
  int lane = threadIdx.x & 31;
  int beg = offs[n], end = offs[n + 1];

  float s0 = 0.f, s1 = 0.f;
  float4 acc0 = make_float4(0.f, 0.f, 0.f, 0.f);
  float4 acc1 = make_float4(0.f, 0.f, 0.f, 0.f);
  const unsigned short* zp = z + lane * 4;
  for (int j = beg; j < end; j += 8) {
    int2 pr[8];
#pragma unroll
    for (int u = 0; u < 8; ++u) pr[u] = csr[min(j + u, end - 1)];
    float4 zv[8];
#pragma unroll
    for (int u = 0; u < 8; ++u) zv[u] = loadV4(zp + (size_t)pr[u].x * D);
#pragma unroll
    for (int u = 0; u < 8; u += 2) {
      float wa = (j + u < end) ? __int_as_float(pr[u].y) : 0.f;
      float wb = (j + u + 1 < end) ? __int_as_float(pr[u + 1].y) : 0.f;
      s0 += wa;
      acc0.x += wa * zv[u].x;
      acc0.y += wa * zv[u].y;
      acc0.z += wa * zv[u].z;
      acc0.w += wa * zv[u].w;
      s1 += wb;
      acc1.x += wb * zv[u + 1].x;
      acc1.y += wb * zv[u + 1].y;
      acc1.z += wb * zv[u + 1].z;
      acc1.w += wb * zv[u + 1].w;
    }
  }
  float s = s0 + s1;
  float inv = (s > 0.f) ? 1.f / s : 0.f;
  float4 acc = make_float4(acc0.x + acc1.x, acc0.y + acc1.y, acc0.z + acc1.z,
                           acc0.w + acc1.w);
  float4 ziv = loadV4(ziin + (size_t)n * D + lane * 4);
  float4 o4;
  o4.x = fmaxf(ziv.x + acc.x * inv, 0.f);
  o4.y = fmaxf(ziv.y + acc.y * inv, 0.f);
  o4.z = fmaxf(ziv.z + acc.z * inv, 0.f);
  o4.w = fmaxf(ziv.w + acc.w * inv, 0.f);
  storeV4(hout + (size_t)n * D + lane * 4, o4);
}

// ---------------------------------------------------------------------------
extern "C" void kernel_launch(void* const* d_in, const int* in_sizes, int n_in,
                              void* d_out, int out_size, void* d_ws,
                              size_t ws_size, hipStream_t stream) {
  const float* attr = (const float*)d_in[0];
  const float* d0 = (const float*)d_in[1];
  const float* d1 = (const float*)d_in[2];
  const int* src0 = (const int*)d_in[3];
  const int* dst0 = (const int*)d_in[4];
  const int* src1 = (const int*)d_in[5];
  const int* dst1 = (const int*)d_in[6];
  const float* W0 = (const float*)d_in[9];
  const float* U0 = (const float*)d_in[10];
  const float* V0 = (const float*)d_in[11];
  const float* a0 = (const float*)d_in[12];
  const float* W1 = (const float*)d_in[13];
  const float* U1 = (const float*)d_in[14];
  const float* V1 = (const float*)d_in[15];
  const float* a1 = (const float*)d_in[16];

  const int N0 = in_sizes[0] / D;  // 100000
  const int E0 = in_sizes[1];      // 640000
  const int E1 = in_sizes[2];      // 320000
  const int ND0 = 40000;
  const int ND1 = 20000;

  char* p = (char*)d_ws;
  auto alloc = [&](size_t bytes) {
    char* q = p;
    p += (bytes + 255) & ~(size_t)255;
    return q;
  };
  unsigned short* z = (unsigned short*)alloc((size_t)N0 * D * 2);  // 25.6MB
  int2* csr = (int2*)alloc((size_t)E0 * 8);                        // 5.12MB
  unsigned short* h1b = (unsigned short*)alloc((size_t)ND0 * D * 2);  // 10.2MB
  int* rank0 = (int*)alloc((size_t)E0 * 4);                           // 2.56MB
  int* rank1 = (int*)alloc((size_t)E1 * 4);                           // 1.28MB
  float* zs = (float*)alloc((size_t)N0 * 4);
  float* zd = (float*)alloc((size_t)N0 * 4);
  int* offs0 = (int*)alloc((size_t)(ND0 + 1) * 4);
  int* offs1 = (int*)alloc((size_t)(ND1 + 1) * 4);
  int* cnt01 = (int*)alloc((size_t)(ND0 + ND1) * 4);  // 240KB
  int* part = (int*)alloc((size_t)128 * 4);           // 64 per layer
  __bf16* wb = (__bf16*)alloc((size_t)4 * D * D * 2);  // W0,U0,W1,U1 bf16
  int* cnt0 = cnt01;
  int* cnt1 = cnt01 + ND0;
  (void)n_in;
  (void)out_size;
  (void)ws_size;

  float* out = (float*)d_out;

  // ---- front matter: weights cvt + cnt zero in ONE launch ----
  {
    int tot = 65536 + ND0 + ND1;
    cvt4_zero_kernel<<<(tot + 255) / 256, 256, 0, stream>>>(
        W0, U0, W1, U1, wb, cnt01, ND0 + ND1);
  }
  const __bf16* W0b = wb;
  const __bf16* U0b = wb + 16384;
  const __bf16* W1b = wb + 32768;
  const __bf16* U1b = wb + 49152;

  // ---- layer 0 GEMM fused with ALL counts (L0 + L1) ----
  {
    int q0 = E0 / 4, q1 = E1 / 4;     // 160000, 80000 (exact)
    int nC = (q0 + q1 + 255) / 256;   // 938
    int n_wb = (N0 + 63) / 64;        // 1563
    int n_ub = (ND0 + 63) / 64;       // 625
    int total = n_wb + n_ub + nC;     // 3126
    int IL = total / nC;              // 3
    gemm_count<float, unsigned short><<<total, 256, 0, stream>>>(
        attr, W0b, U0b, z, (unsigned short*)d_out, a0, zs, zd, n_wb, N0, ND0,
        dst0, dst1, cnt0, cnt1, rank0, rank1, q0, q1, IL, nC);
  }
  // ---- both layers' scans ----
  {
    int nb0 = (ND0 + 1023) / 1024;  // 40
    int nb1 = (ND1 + 1023) / 1024;  // 20
    scan_partial2<<<nb0 + nb1, 256, 0, stream>>>(cnt0, cnt1, part, nb0, ND0,
                                                 ND1);
    scan_final2<<<nb0 + nb1, 256, 0, stream>>>(cnt0, cnt1, part, offs0, offs1,
                                               nb0, ND0, ND1, E0, E1);
  }
  // ---- layer 0: scatter + aggregate ----
  scatter_w_kernel<<<(E0 / 4 + 255) / 256, 256, 0, stream>>>(
      src0, dst0, d0, zs, zd, V0, a0, rank0, offs0, csr, E0);
  gat_perdst<unsigned short><<<(ND0 + 7) / 8, 256, 0, stream>>>(
      z, csr, offs0, (const unsigned short*)d_out, h1b, ND0);

  // ---- layer 1 (pure gemm via nC=0) ----
  {
    int n_wb = (ND0 + 63) / 64, n_ub = (ND1 + 63) / 64;  // 625 + 313
    gemm_count<unsigned short, float><<<n_wb + n_ub, 256, 0, stream>>>(
        h1b, W1b, U1b, z, out, a1, zs, zd, n_wb, ND0, ND1, nullptr, nullptr,
        nullptr, nullptr, nullptr, nullptr, 0, 0, 1, 0);
  }
  scatter_w_kernel<<<(E1 / 4 + 255) / 256, 256, 0, stream>>>(
      src1, dst1, d1, zs, zd, V1, a1, rank1, offs1, csr, E1);
  gat_perdst<float><<<(ND1 + 7) / 8, 256, 0, stream>>>(z, csr, offs1, out, out,
                                                       ND1);
}